// Round 6
// baseline (363.679 us; speedup 1.0000x reference)
//
#include <hip/hip_runtime.h>

#define BATCH 128
#define NBOX 8732
#define NC 21
#define M (BATCH * NBOX)            // 1,117,696
#define EBLK 2048                   // k_elem grid (16 blocks per batch)
#define SUBB 16
#define CHUNK 546                   // rows per block; last block of batch: 542
#define NREP1 32                    // L1 replicas (k_elem flush, 2048 blocks)
#define NREP2 8                     // L2/L3 replicas (k_hist flush, 1024 blocks)
#define CLIP_MAX 16.118095651f     // -log(1e-7)

struct Ctl {
  float pos_conf_sum, pos_loc_sum, s_gt, denom;
  unsigned int k_rem, d1, d2, pad;
};

// ws layout: [ctl 1KB][replicas 768KB (zeroed)][partials][MC][CL]
#define OFF_REP 1024
#define R1SZ    (NREP1 * 2048 * 4)       // 256 KB
#define R23SZ   (NREP2 * 2048 * 4)       // 64 KB
#define OFF_R1C (OFF_REP)
#define OFF_R1S (OFF_R1C + R1SZ)
#define OFF_R2C (OFF_R1S + R1SZ)
#define OFF_R2S (OFF_R2C + R23SZ)
#define OFF_R3C (OFF_R2S + R23SZ)
#define OFF_R3S (OFF_R3C + R23SZ)
#define OFF_NPP (OFF_R3S + R23SZ)        // partials: fully overwritten, not zeroed
#define OFF_PCP (OFF_NPP + 8192)
#define OFF_PLP (OFF_PCP + 8192)
#define OFF_MC  (OFF_PLP + 8192)
#define OFF_CL  (OFF_MC + M * 4)
#define ZERO_BYTES OFF_NPP               // 787,456 B

// 33-bit linear fixed-point key over [0,1): monotone in mc, injective for mc>2^-10
__device__ __forceinline__ unsigned long long mckey(float mc) {
  unsigned long long K = (unsigned long long)((double)mc * 8589934592.0);  // *2^33
  return (K > 0x1FFFFFFFFull) ? 0x1FFFFFFFFull : K;
}

// ---------------------------------------------------------------------------
// Fused elementwise + L1 histogram. Wave-cooperative: one row per 32-lane
// group, lane j = class j. All global loads are intra-row contiguous (2-3
// cache lines per wave instruction instead of ~43).
// ---------------------------------------------------------------------------
__global__ __launch_bounds__(256) void k_elem(
    const float* __restrict__ yt, const float* __restrict__ lp,
    const float* __restrict__ cp, float* __restrict__ MC,
    float* __restrict__ CL, float* __restrict__ np_part,
    float* __restrict__ pc_part, float* __restrict__ pl_part,
    unsigned int* __restrict__ rep1c, float* __restrict__ rep1s) {
  __shared__ unsigned int hc[2048];
  __shared__ float hs[2048];
  __shared__ float sred[12];
  const int tid = threadIdx.x;
  const int bid = blockIdx.x;
  for (int i = tid; i < 2048; i += 256) { hc[i] = 0u; hs[i] = 0.f; }
  __syncthreads();

  const int batch = bid >> 4;
  const int sub = bid & 15;
  const int base = batch * NBOX + sub * CHUNK;
  const int cnt = (sub == SUBB - 1) ? (NBOX - (SUBB - 1) * CHUNK) : CHUNK;
  const int g = tid >> 5;     // 8 groups of 32 lanes per block
  const int j = tid & 31;     // class / word index within the row

  float tpc = 0.f, tpl = 0.f, tnp = 0.f;
  for (int i = g; i < cnt; i += 8) {
    const int r = base + i;
    // contiguous predicated loads: 84 B + 104 B + 16 B per row
    float cv = -1e30f, yw = 0.f, lvj = 0.f;
    if (j < NC) cv = cp[(size_t)r * NC + j];     // logit j
    if (j < 26) yw = yt[(size_t)r * 26 + j];     // y_true word j
    if (j < 4)  lvj = lp[(size_t)r * 4 + j];     // loc_pred j
    const float pos = __shfl(yw, 25, 32);
    const float oh  = __shfl(yw, j + 4, 32);     // onehot[class j] (valid j<21)

    // group max of logits (idle lanes carry -1e30)
    float mx = cv;
    mx = fmaxf(mx, __shfl_xor(mx, 1, 32));
    mx = fmaxf(mx, __shfl_xor(mx, 2, 32));
    mx = fmaxf(mx, __shfl_xor(mx, 4, 32));
    mx = fmaxf(mx, __shfl_xor(mx, 8, 32));
    mx = fmaxf(mx, __shfl_xor(mx, 16, 32));

    float ee = 0.f, pt = 0.f, sl = 0.f;
    if (j < NC) { ee = __expf(cv - mx); pt = oh * cv; }
    if (j < 4) {
      const float d = yw - lvj, ad = fabsf(d);
      sl = (ad < 1.f) ? 0.5f * d * d : ad - 0.5f;
    }
    const float e0 = __shfl(ee, 0, 32);          // exp(logit0 - mx)
    // triple sum-reduce: ssum, plogit, loc-loss
    float ssum = ee, plog = pt, ll = sl;
#pragma unroll
    for (int m = 1; m < 32; m <<= 1) {
      ssum += __shfl_xor(ssum, m, 32);
      plog += __shfl_xor(plog, m, 32);
      ll   += __shfl_xor(ll, m, 32);
    }

    const float cl = fminf(mx + __logf(ssum) - plog, CLIP_MAX);
    const float mc = (1.f - pos) * ((ssum - e0) / ssum);

    if (j == 0) {
      MC[r] = mc;
      CL[r] = cl;
      const unsigned int b1 = (unsigned int)(mckey(mc) >> 22);  // top 11 bits
      atomicAdd(&hc[b1], 1u);
      atomicAdd(&hs[b1], cl);
      tpc += pos * cl;
      tpl += pos * ll;
      tnp += pos;
    }
  }

  // block-reduce the three scalars -> per-block partial arrays (no global atomics)
#pragma unroll
  for (int off = 32; off > 0; off >>= 1) {
    tpc += __shfl_down(tpc, off);
    tpl += __shfl_down(tpl, off);
    tnp += __shfl_down(tnp, off);
  }
  if ((tid & 63) == 0) {
    const int w = tid >> 6;
    sred[w] = tpc; sred[4 + w] = tpl; sred[8 + w] = tnp;
  }
  __syncthreads();
  if (tid == 0) {
    pc_part[bid] = sred[0] + sred[1] + sred[2] + sred[3];
    pl_part[bid] = sred[4] + sred[5] + sred[6] + sred[7];
    np_part[bid] = sred[8] + sred[9] + sred[10] + sred[11];
  }
  // flush LDS hist into replica (bid & 31): same-address chains <= 64
  unsigned int* rc = rep1c + (bid & (NREP1 - 1)) * 2048;
  float* rs = rep1s + (bid & (NREP1 - 1)) * 2048;
  for (int i = tid; i < 2048; i += 256)
    if (hc[i]) { atomicAdd(&rc[i], hc[i]); atomicAdd(&rs[i], hs[i]); }
}

// ---------------------------------------------------------------------------
// Refinement histograms for radix levels 2/3 (filter by prefix digits).
// ---------------------------------------------------------------------------
template <int LEVEL>
__global__ __launch_bounds__(256) void k_hist(
    const float* __restrict__ MC, const float* __restrict__ CL,
    unsigned int* __restrict__ repc, float* __restrict__ reps,
    const Ctl* __restrict__ ctl) {
  __shared__ unsigned int hc[2048];
  __shared__ float hs[2048];
  for (int i = threadIdx.x; i < 2048; i += 256) { hc[i] = 0u; hs[i] = 0.f; }
  __syncthreads();
  const unsigned int dd = (LEVEL == 2) ? ctl->d1 : ((ctl->d1 << 11) | ctl->d2);
  const float4* M4 = (const float4*)MC;
  const int n4 = M / 4;
  const int stride = gridDim.x * 256;
  for (int i = blockIdx.x * 256 + threadIdx.x; i < n4; i += stride) {
    const float4 m = M4[i];
    const float mv[4] = {m.x, m.y, m.z, m.w};
#pragma unroll
    for (int q = 0; q < 4; ++q) {
      const unsigned long long K = mckey(mv[q]);
      bool match; unsigned int bin;
      if (LEVEL == 2) { match = (unsigned int)(K >> 22) == dd; bin = (unsigned int)(K >> 11) & 2047u; }
      else            { match = (unsigned int)(K >> 11) == dd; bin = (unsigned int)K & 2047u; }
      if (match) {            // rare (~1/2048 of elements)
        const float cl = CL[4 * i + q];
        atomicAdd(&hc[bin], 1u);
        atomicAdd(&hs[bin], cl);
      }
    }
  }
  __syncthreads();
  unsigned int* rc = repc + (blockIdx.x & (NREP2 - 1)) * 2048;
  float* rs = reps + (blockIdx.x & (NREP2 - 1)) * 2048;
  for (int i = threadIdx.x; i < 2048; i += 256)
    if (hc[i]) { atomicAdd(&rc[i], hc[i]); atomicAdd(&rs[i], hs[i]); }
}

// ---------------------------------------------------------------------------
// Scan: reduce replicas, suffix-scan counts, pick k-th-largest bin, accumulate
// CL-sum of fully-selected bins. L1 computes k/denom/pos-sums; L3 emits output.
// ---------------------------------------------------------------------------
template <int LEVEL, int NREP>
__global__ __launch_bounds__(1024) void k_scan(
    const unsigned int* __restrict__ repc, const float* __restrict__ reps,
    const float* __restrict__ np_part, const float* __restrict__ pc_part,
    const float* __restrict__ pl_part, Ctl* __restrict__ ctl,
    float* __restrict__ out) {
  __shared__ unsigned int s[2048];
  __shared__ float sf[2048];
  __shared__ float red[16], rn[16], rh[16], rc[16], ra[16], rb[16];
  __shared__ unsigned int kk;
  __shared__ int win;
  const int tid = threadIdx.x;

  // reduce replicas (coalesced sweeps)
  unsigned int c0 = 0, c1 = 0;
  float f0 = 0.f, f1 = 0.f;
  for (int r = 0; r < NREP; ++r) {
    c0 += repc[r * 2048 + tid];
    c1 += repc[r * 2048 + tid + 1024];
    f0 += reps[r * 2048 + tid];
    f1 += reps[r * 2048 + tid + 1024];
  }
  s[tid] = c0; s[tid + 1024] = c1;
  sf[tid] = f0; sf[tid + 1024] = f1;

  if (LEVEL == 1) {
    float np = 0.f;
    if (tid < BATCH)
      for (int jj = 0; jj < SUBB; ++jj) np += np_part[tid * SUBB + jj];
    float nn  = fminf(3.0f * np, (float)NBOX - np);   // 0 for tid>=BATCH
    float hp  = (np > 0.f) ? 1.f : 0.f;
    float npc = (tid < BATCH) ? ((np != 0.f) ? np : 1.f) : 0.f;
    float a = pc_part[tid] + pc_part[tid + 1024];
    float b = pl_part[tid] + pl_part[tid + 1024];
#pragma unroll
    for (int off = 32; off > 0; off >>= 1) {
      nn += __shfl_down(nn, off);   hp += __shfl_down(hp, off);
      npc += __shfl_down(npc, off); a += __shfl_down(a, off);
      b += __shfl_down(b, off);
    }
    const int w = tid >> 6;
    if ((tid & 63) == 0) { rn[w] = nn; rh[w] = hp; rc[w] = npc; ra[w] = a; rb[w] = b; }
    __syncthreads();
    if (tid == 0) {
      float tn = 0.f, th = 0.f, tc = 0.f, ta = 0.f, tb = 0.f;
      for (int i = 0; i < 16; ++i) { tn += rn[i]; th += rh[i]; tc += rc[i]; ta += ra[i]; tb += rb[i]; }
      ctl->denom = tc;
      ctl->pos_conf_sum = ta;
      ctl->pos_loc_sum = tb;
      kk = (unsigned int)floorf((th > 0.f) ? tn : 100.0f);   // NEG_FOR_HARD
    }
  } else {
    if (tid == 0) kk = ctl->k_rem;
  }
  if (tid == 0) win = -1;
  __syncthreads();

  const unsigned int krem = kk;   // uniform
  if (krem != 0) {
    // inclusive suffix scan (Hillis-Steele), barriered read/write phases
    for (int off = 1; off < 2048; off <<= 1) {
      const unsigned int v0 = (tid + off < 2048) ? s[tid + off] : 0u;
      const unsigned int v1 = (tid + 1024 + off < 2048) ? s[tid + 1024 + off] : 0u;
      __syncthreads();
      s[tid] += v0;
      s[tid + 1024] += v1;
      __syncthreads();
    }
    // unique bin b*: suffix[b*] >= k > suffix[b*+1]
#pragma unroll
    for (int t = 0; t < 2; ++t) {
      const int i = tid + t * 1024;
      const unsigned int si = s[i];
      const unsigned int sn = (i < 2047) ? s[i + 1] : 0u;
      if (si >= krem && sn < krem) win = i;
    }
    __syncthreads();
    const int b = win;   // uniform
    float acc = 0.f;     // CL sum of fully-selected bins (strictly above b*)
    if (b >= 0) {
      if (tid > b) acc += sf[tid];
      if (tid + 1024 > b) acc += sf[tid + 1024];
    }
#pragma unroll
    for (int off = 32; off > 0; off >>= 1) acc += __shfl_down(acc, off);
    if ((tid & 63) == 0) red[tid >> 6] = acc;
    __syncthreads();
    if (tid == 0 && b >= 0) {
      float tot = 0.f;
      for (int i = 0; i < 16; ++i) tot += red[i];
      const unsigned int above = (b < 2047) ? s[b + 1] : 0u;
      const unsigned int krem2 = krem - above;
      if (LEVEL < 3) {
        ctl->s_gt += tot;
        ctl->k_rem = krem2;
        if (LEVEL == 1) ctl->d1 = (unsigned int)b;
        else            ctl->d2 = (unsigned int)b;
      } else {
        const unsigned int neq = s[b] - above;   // bit-exact ties
        const float tie = (neq > 0) ? sf[b] * ((float)krem2 / (float)neq) : 0.f;
        const float neg = ctl->s_gt + tot + tie;
        out[0] = (ctl->pos_conf_sum + neg + ctl->pos_loc_sum) / ctl->denom;
      }
    }
  } else if (LEVEL == 3 && tid == 0) {   // defensive: k==0 cannot occur
    out[0] = (ctl->pos_conf_sum + ctl->s_gt + ctl->pos_loc_sum) / ctl->denom;
  }
}

// ---------------------------------------------------------------------------
extern "C" void kernel_launch(void* const* d_in, const int* in_sizes, int n_in,
                              void* d_out, int out_size, void* d_ws, size_t ws_size,
                              hipStream_t stream) {
  const float* yt = (const float*)d_in[0];   // y_true    (B,N,26)
  const float* lp = (const float*)d_in[1];   // loc_pred  (B,N,4)
  const float* cp = (const float*)d_in[2];   // conf_pred (B,N,21)
  float* out = (float*)d_out;

  char* ws = (char*)d_ws;
  Ctl* ctl = (Ctl*)ws;
  unsigned int* rep1c = (unsigned int*)(ws + OFF_R1C);
  float*        rep1s = (float*)(ws + OFF_R1S);
  unsigned int* rep2c = (unsigned int*)(ws + OFF_R2C);
  float*        rep2s = (float*)(ws + OFF_R2S);
  unsigned int* rep3c = (unsigned int*)(ws + OFF_R3C);
  float*        rep3s = (float*)(ws + OFF_R3S);
  float* np_part = (float*)(ws + OFF_NPP);
  float* pc_part = (float*)(ws + OFF_PCP);
  float* pl_part = (float*)(ws + OFF_PLP);
  float* MC = (float*)(ws + OFF_MC);
  float* CL = (float*)(ws + OFF_CL);

  hipMemsetAsync(ws, 0, ZERO_BYTES, stream);   // ctl + replicas only (0.77 MB)
  k_elem<<<EBLK, 256, 0, stream>>>(yt, lp, cp, MC, CL, np_part, pc_part, pl_part,
                                   rep1c, rep1s);
  k_scan<1, NREP1><<<1, 1024, 0, stream>>>(rep1c, rep1s, np_part, pc_part, pl_part, ctl, out);
  k_hist<2><<<1024, 256, 0, stream>>>(MC, CL, rep2c, rep2s, ctl);
  k_scan<2, NREP2><<<1, 1024, 0, stream>>>(rep2c, rep2s, np_part, pc_part, pl_part, ctl, out);
  k_hist<3><<<1024, 256, 0, stream>>>(MC, CL, rep3c, rep3s, ctl);
  k_scan<3, NREP2><<<1, 1024, 0, stream>>>(rep3c, rep3s, np_part, pc_part, pl_part, ctl, out);
}

// Round 7
// 302.516 us; speedup vs baseline: 1.2022x; 1.2022x over previous
//
#include <hip/hip_runtime.h>

#define BATCH 128
#define NBOX 8732
#define NC 21
#define M (BATCH * NBOX)            // 1,117,696 = 4366 * 256
#define RPB 256
#define NBLK (M / RPB)              // 4366
#define NREP1 32                    // L1 replicas
#define NREP2 8                     // L2/L3 replicas
#define NB1 1024                    // L1 bins (10 bits)
#define NB23 2048                   // L2/L3 bins (11 bits)
#define CLIP_MAX 16.118095651f      // -log(1e-7)

struct Ctl {
  float num_pos[BATCH];
  float pos_conf_sum, pos_loc_sum, s_gt, denom;
  unsigned int k_rem, d1, d2, pad;
};

// ws layout: [ctl 1KB][rep1 c/s 2x128KB][rep2 c/s 2x64KB][rep3 c/s 2x64KB]
//            [pc_part][pl_part][MC][CL]; zero only through the replicas.
#define OFF_R1C 1024
#define R1SZ    (NREP1 * NB1 * 4)        // 131072
#define R23SZ   (NREP2 * NB23 * 4)       // 65536
#define OFF_R1S (OFF_R1C + R1SZ)
#define OFF_R2C (OFF_R1S + R1SZ)
#define OFF_R2S (OFF_R2C + R23SZ)
#define OFF_R3C (OFF_R2S + R23SZ)
#define OFF_R3S (OFF_R3C + R23SZ)
#define OFF_PCP (OFF_R3S + R23SZ)
#define ZERO_BYTES OFF_PCP               // 525,312 B
#define OFF_PLP (OFF_PCP + 17472)        // 4366*4 rounded to 64
#define OFF_MC  (OFF_PLP + 17472)
#define OFF_CL  (OFF_MC + M * 4)

// 32-bit linear fixed-point key over [0,1]: monotone in mc; injective for all
// floats mc > 2^-8 (float spacing there > 2^-32 grid). Threshold sits at
// mc ~0.5-1.0, far from the collision region. Digits: 10 | 11 | 11.
__device__ __forceinline__ unsigned int mckey(float mc) {
  unsigned long long K = (unsigned long long)((double)mc * 4294967296.0);
  return (K > 0xFFFFFFFFull) ? 0xFFFFFFFFu : (unsigned int)K;
}

// ---------------------------------------------------------------------------
// Fused elementwise + L1 histogram. Coalesced staging (float4/float2) into
// LDS with on-the-fly y_true decode (loc4 + pos + label); per-thread-row
// compute from LDS (one row per thread, no loops, no hot barriers).
// ---------------------------------------------------------------------------
__global__ __launch_bounds__(256) void k_elem(
    const float* __restrict__ yt, const float* __restrict__ lp,
    const float* __restrict__ cp, float* __restrict__ MC,
    float* __restrict__ CL, float* __restrict__ pc_part,
    float* __restrict__ pl_part, unsigned int* __restrict__ rep1c,
    float* __restrict__ rep1s, Ctl* __restrict__ ctl) {
  __shared__ float s_cp[RPB * NC];     // 21504 B, read stride 21 -> 2-way (free)
  __shared__ float s_loc[RPB * 4];     // 4096 B, read as float4 contiguous
  __shared__ float s_pos[RPB];         // 1024 B
  __shared__ int   s_lab[RPB];         // 1024 B (exactly one writer per row)
  __shared__ unsigned int hc[NB1];     // 4096 B
  __shared__ float hs[NB1];            // 4096 B
  __shared__ float sred[16];           // ~35.9 KB total -> 4 blocks/CU

  const int tid = threadIdx.x;
  const int bid = blockIdx.x;
  const int e = bid * RPB + tid;

  // issue the independent global load early (overlaps staging latency)
  const float4 lv = ((const float4*)lp)[e];    // loc_pred row, 16B aligned

  for (int i = tid; i < NB1; i += 256) { hc[i] = 0u; hs[i] = 0.f; }

  // conf_pred chunk: 256*21*4 B = 1344 aligned float4 (base = bid*21504)
  {
    const float4* gc = (const float4*)(cp + (size_t)bid * RPB * NC);
    float4* sc = (float4*)s_cp;
    for (int i = tid; i < RPB * NC / 4; i += 256) sc[i] = gc[i];
  }
  // y_true chunk: 256 rows * 13 float2 (base = bid*26624, 8B aligned).
  // float2 i covers words jj=2*(i%13), jj+1 of row r=i/13:
  //   0-3 loc | 4-24 onehot(class=word-4) | 25 pos
  {
    const float2* gy = (const float2*)(yt + (size_t)bid * RPB * 26);
    for (int i = tid; i < RPB * 13; i += 256) {
      const float2 v = gy[i];
      const int r = i / 13;             // const-divisor -> mul_hi
      const int jj = 2 * (i - r * 13);
      if (jj == 0)       { s_loc[4 * r] = v.x;     s_loc[4 * r + 1] = v.y; }
      else if (jj == 2)  { s_loc[4 * r + 2] = v.x; s_loc[4 * r + 3] = v.y; }
      else if (jj == 24) { if (v.x > 0.5f) s_lab[r] = 20; s_pos[r] = v.y; }
      else {             // jj in [4,22]: onehot classes jj-4, jj-3
        if (v.x > 0.5f) s_lab[r] = jj - 4;
        if (v.y > 0.5f) s_lab[r] = jj - 3;
      }
    }
  }
  __syncthreads();

  const float4 tv = *(const float4*)(s_loc + 4 * tid);
  const float pos = s_pos[tid];
  const int lab = s_lab[tid];

  // smooth-L1 loc loss
  float ll;
  {
    const float d0 = tv.x - lv.x, d1 = tv.y - lv.y, d2 = tv.z - lv.z, d3 = tv.w - lv.w;
    const float a0 = fabsf(d0), a1 = fabsf(d1), a2 = fabsf(d2), a3 = fabsf(d3);
    ll  = (a0 < 1.f) ? 0.5f * d0 * d0 : a0 - 0.5f;
    ll += (a1 < 1.f) ? 0.5f * d1 * d1 : a1 - 0.5f;
    ll += (a2 < 1.f) ? 0.5f * d2 * d2 : a2 - 0.5f;
    ll += (a3 < 1.f) ? 0.5f * d3 * d3 : a3 - 0.5f;
  }

  // softmax stats from LDS (per-thread row; static/LDS indexing only)
  const float* c = s_cp + tid * NC;
  float mx = c[0];
#pragma unroll
  for (int j = 1; j < NC; ++j) mx = fmaxf(mx, c[j]);
  float ssum = 0.f, e0 = 0.f;
#pragma unroll
  for (int j = 0; j < NC; ++j) {
    const float ee = __expf(c[j] - mx);
    ssum += ee;
    if (j == 0) e0 = ee;
  }
  const float plogit = c[lab];               // dynamic LDS index: fine
  const float cl = fminf(mx + __logf(ssum) - plogit, CLIP_MAX);
  const float mc = (1.f - pos) * ((ssum - e0) / ssum);

  MC[e] = mc;   // coalesced dword stores
  CL[e] = cl;
  const unsigned int b1 = mckey(mc) >> 22;   // top 10 bits
  atomicAdd(&hc[b1], 1u);
  atomicAdd(&hs[b1], cl);

  // block reductions; a block spans at most 2 batches
  const int b0 = (bid * RPB) / NBOX;
  float np0 = (e < (b0 + 1) * NBOX) ? pos : 0.f;
  float np1 = pos - np0;
  float tpc = pos * cl, tpl = pos * ll;
#pragma unroll
  for (int off = 32; off > 0; off >>= 1) {
    tpc += __shfl_down(tpc, off);
    tpl += __shfl_down(tpl, off);
    np0 += __shfl_down(np0, off);
    np1 += __shfl_down(np1, off);
  }
  if ((tid & 63) == 0) {
    const int w = tid >> 6;
    sred[w] = tpc; sred[4 + w] = tpl; sred[8 + w] = np0; sred[12 + w] = np1;
  }
  __syncthreads();   // also orders LDS hist atomics before flush
  if (tid == 0) {
    pc_part[bid] = sred[0] + sred[1] + sred[2] + sred[3];
    pl_part[bid] = sred[4] + sred[5] + sred[6] + sred[7];
    const float n0 = sred[8] + sred[9] + sred[10] + sred[11];
    const float n1 = sred[12] + sred[13] + sred[14] + sred[15];
    // sparse global atomics: <=2 per block over 128 addresses
    if (n0 != 0.f) atomicAdd(&ctl->num_pos[b0], n0);
    if (n1 != 0.f && b0 + 1 < BATCH) atomicAdd(&ctl->num_pos[b0 + 1], n1);
  }
  // flush LDS hist into replica (bid & 31): same-address chains <= 137
  unsigned int* rc = rep1c + (bid & (NREP1 - 1)) * NB1;
  float* rs = rep1s + (bid & (NREP1 - 1)) * NB1;
  for (int i = tid; i < NB1; i += 256)
    if (hc[i]) { atomicAdd(&rc[i], hc[i]); atomicAdd(&rs[i], hs[i]); }
}

// ---------------------------------------------------------------------------
// Refinement histograms for radix levels 2/3 (filter by prefix digits).
// ---------------------------------------------------------------------------
template <int LEVEL>
__global__ __launch_bounds__(256) void k_hist(
    const float* __restrict__ MC, const float* __restrict__ CL,
    unsigned int* __restrict__ repc, float* __restrict__ reps,
    const Ctl* __restrict__ ctl) {
  __shared__ unsigned int hc[NB23];
  __shared__ float hs[NB23];
  for (int i = threadIdx.x; i < NB23; i += 256) { hc[i] = 0u; hs[i] = 0.f; }
  __syncthreads();
  const unsigned int dd = (LEVEL == 2) ? ctl->d1 : ((ctl->d1 << 11) | ctl->d2);
  const float4* M4 = (const float4*)MC;
  const int n4 = M / 4;
  const int stride = gridDim.x * 256;
  for (int i = blockIdx.x * 256 + threadIdx.x; i < n4; i += stride) {
    const float4 m = M4[i];
    const float mv[4] = {m.x, m.y, m.z, m.w};
#pragma unroll
    for (int q = 0; q < 4; ++q) {
      const unsigned int K = mckey(mv[q]);
      bool match; unsigned int bin;
      if (LEVEL == 2) { match = (K >> 22) == dd; bin = (K >> 11) & 2047u; }
      else            { match = (K >> 11) == dd; bin = K & 2047u; }
      if (match) {            // rare (~1/1024 resp ~1/2M of elements)
        const float cl = CL[4 * i + q];
        atomicAdd(&hc[bin], 1u);
        atomicAdd(&hs[bin], cl);
      }
    }
  }
  __syncthreads();
  unsigned int* rc = repc + (blockIdx.x & (NREP2 - 1)) * NB23;
  float* rs = reps + (blockIdx.x & (NREP2 - 1)) * NB23;
  for (int i = threadIdx.x; i < NB23; i += 256)
    if (hc[i]) { atomicAdd(&rc[i], hc[i]); atomicAdd(&rs[i], hs[i]); }
}

// ---------------------------------------------------------------------------
// Scan: reduce replicas, suffix-scan counts, pick the k-th-largest bin,
// accumulate CL of fully-selected bins. L1 computes k/denom/pos-sums from
// partials; L3 emits the final scalar.
// ---------------------------------------------------------------------------
template <int LEVEL, int NREP, int NBINS>
__global__ __launch_bounds__(1024) void k_scan(
    const unsigned int* __restrict__ repc, const float* __restrict__ reps,
    const float* __restrict__ pc_part, const float* __restrict__ pl_part,
    Ctl* __restrict__ ctl, float* __restrict__ out) {
  __shared__ unsigned int s[2048];
  __shared__ float sf[2048];
  __shared__ float red[16], rn[16], rh[16], rc[16], ra[16], rb[16];
  __shared__ unsigned int kk;
  __shared__ int win;
  const int tid = threadIdx.x;

  // reduce replicas (coalesced sweeps); zero-fill unused upper bins
  unsigned int c0 = 0, c1 = 0;
  float f0 = 0.f, f1 = 0.f;
  for (int r = 0; r < NREP; ++r) {
    c0 += repc[r * NBINS + tid];
    f0 += reps[r * NBINS + tid];
    if (NBINS > 1024) {
      c1 += repc[r * NBINS + tid + 1024];
      f1 += reps[r * NBINS + tid + 1024];
    }
  }
  s[tid] = c0; s[tid + 1024] = c1;
  sf[tid] = f0; sf[tid + 1024] = f1;

  if (LEVEL == 1) {
    const float np = (tid < BATCH) ? ctl->num_pos[tid] : 0.f;
    float nn  = fminf(3.0f * np, (float)NBOX - np);   // 0 for tid>=BATCH
    float hp  = (np > 0.f) ? 1.f : 0.f;
    float npc = (tid < BATCH) ? ((np != 0.f) ? np : 1.f) : 0.f;
    float a = 0.f, b = 0.f;
    for (int i = tid; i < NBLK; i += 1024) { a += pc_part[i]; b += pl_part[i]; }
#pragma unroll
    for (int off = 32; off > 0; off >>= 1) {
      nn += __shfl_down(nn, off);   hp += __shfl_down(hp, off);
      npc += __shfl_down(npc, off); a += __shfl_down(a, off);
      b += __shfl_down(b, off);
    }
    const int w = tid >> 6;
    if ((tid & 63) == 0) { rn[w] = nn; rh[w] = hp; rc[w] = npc; ra[w] = a; rb[w] = b; }
    __syncthreads();
    if (tid == 0) {
      float tn = 0.f, th = 0.f, tc = 0.f, ta = 0.f, tb = 0.f;
      for (int i = 0; i < 16; ++i) { tn += rn[i]; th += rh[i]; tc += rc[i]; ta += ra[i]; tb += rb[i]; }
      ctl->denom = tc;
      ctl->pos_conf_sum = ta;
      ctl->pos_loc_sum = tb;
      kk = (unsigned int)floorf((th > 0.f) ? tn : 100.0f);   // NEG_FOR_HARD
    }
  } else {
    if (tid == 0) kk = ctl->k_rem;
  }
  if (tid == 0) win = -1;
  __syncthreads();

  const unsigned int krem = kk;   // uniform
  if (krem != 0) {
    // inclusive suffix scan (Hillis-Steele), barriered read/write phases
    for (int off = 1; off < 2048; off <<= 1) {
      const unsigned int v0 = (tid + off < 2048) ? s[tid + off] : 0u;
      const unsigned int v1 = (tid + 1024 + off < 2048) ? s[tid + 1024 + off] : 0u;
      __syncthreads();
      s[tid] += v0;
      s[tid + 1024] += v1;
      __syncthreads();
    }
    // unique bin b*: suffix[b*] >= k > suffix[b*+1]
#pragma unroll
    for (int t = 0; t < 2; ++t) {
      const int i = tid + t * 1024;
      const unsigned int si = s[i];
      const unsigned int sn = (i < 2047) ? s[i + 1] : 0u;
      if (si >= krem && sn < krem) win = i;
    }
    __syncthreads();
    const int b = win;   // uniform
    float acc = 0.f;     // CL of fully-selected bins (strictly above b*)
    if (b >= 0) {
      if (tid > b) acc += sf[tid];
      if (tid + 1024 > b) acc += sf[tid + 1024];
    }
#pragma unroll
    for (int off = 32; off > 0; off >>= 1) acc += __shfl_down(acc, off);
    if ((tid & 63) == 0) red[tid >> 6] = acc;
    __syncthreads();
    if (tid == 0 && b >= 0) {
      float tot = 0.f;
      for (int i = 0; i < 16; ++i) tot += red[i];
      const unsigned int above = (b < 2047) ? s[b + 1] : 0u;
      const unsigned int krem2 = krem - above;
      if (LEVEL < 3) {
        ctl->s_gt += tot;
        ctl->k_rem = krem2;
        if (LEVEL == 1) ctl->d1 = (unsigned int)b;
        else            ctl->d2 = (unsigned int)b;
      } else {
        const unsigned int neq = s[b] - above;   // ties are bit-identical keys
        const float tie = (neq > 0) ? sf[b] * ((float)krem2 / (float)neq) : 0.f;
        const float neg = ctl->s_gt + tot + tie;
        out[0] = (ctl->pos_conf_sum + neg + ctl->pos_loc_sum) / ctl->denom;
      }
    }
  } else if (LEVEL == 3 && tid == 0) {   // defensive: k==0 cannot occur
    out[0] = (ctl->pos_conf_sum + ctl->s_gt + ctl->pos_loc_sum) / ctl->denom;
  }
}

// ---------------------------------------------------------------------------
extern "C" void kernel_launch(void* const* d_in, const int* in_sizes, int n_in,
                              void* d_out, int out_size, void* d_ws, size_t ws_size,
                              hipStream_t stream) {
  const float* yt = (const float*)d_in[0];   // y_true    (B,N,26)
  const float* lp = (const float*)d_in[1];   // loc_pred  (B,N,4)
  const float* cp = (const float*)d_in[2];   // conf_pred (B,N,21)
  float* out = (float*)d_out;

  char* ws = (char*)d_ws;
  Ctl* ctl = (Ctl*)ws;
  unsigned int* rep1c = (unsigned int*)(ws + OFF_R1C);
  float*        rep1s = (float*)(ws + OFF_R1S);
  unsigned int* rep2c = (unsigned int*)(ws + OFF_R2C);
  float*        rep2s = (float*)(ws + OFF_R2S);
  unsigned int* rep3c = (unsigned int*)(ws + OFF_R3C);
  float*        rep3s = (float*)(ws + OFF_R3S);
  float* pc_part = (float*)(ws + OFF_PCP);
  float* pl_part = (float*)(ws + OFF_PLP);
  float* MC = (float*)(ws + OFF_MC);
  float* CL = (float*)(ws + OFF_CL);

  hipMemsetAsync(ws, 0, ZERO_BYTES, stream);   // ctl + replicas (0.5 MB)
  k_elem<<<NBLK, 256, 0, stream>>>(yt, lp, cp, MC, CL, pc_part, pl_part,
                                   rep1c, rep1s, ctl);
  k_scan<1, NREP1, NB1><<<1, 1024, 0, stream>>>(rep1c, rep1s, pc_part, pl_part, ctl, out);
  k_hist<2><<<1024, 256, 0, stream>>>(MC, CL, rep2c, rep2s, ctl);
  k_scan<2, NREP2, NB23><<<1, 1024, 0, stream>>>(rep2c, rep2s, pc_part, pl_part, ctl, out);
  k_hist<3><<<1024, 256, 0, stream>>>(MC, CL, rep3c, rep3s, ctl);
  k_scan<3, NREP2, NB23><<<1, 1024, 0, stream>>>(rep3c, rep3s, pc_part, pl_part, ctl, out);
}